// Round 5
// baseline (489.711 us; speedup 1.0000x reference)
//
#include <hip/hip_runtime.h>
#include <math.h>

#define HWP 4096
#define CCH 256
#define NN  1024
#define DD  256
#define ZQ_SIZE (8 * DD * HWP)       // 8388608 floats = 33554432 B
#define MARGIN 2e-3f

typedef _Float16 h8 __attribute__((ext_vector_type(8)));
typedef float    f4 __attribute__((ext_vector_type(4)));

__device__ __forceinline__ void gl_lds16(const _Float16* g, void* lds) {
    __builtin_amdgcn_global_load_lds(
        (const __attribute__((address_space(1))) unsigned int*)(g),
        (__attribute__((address_space(3))) unsigned int*)(lds),
        16, 0, 0);
}

// ---------- K1: split w -> wh/wl fp16 [1024][256] ----------
__global__ __launch_bounds__(256) void split_w_k(
    const float* __restrict__ w, _Float16* __restrict__ wh, _Float16* __restrict__ wl)
{
    const int i = blockIdx.x * 256 + threadIdx.x;
    const float x = w[i];
    const _Float16 h = (_Float16)x;
    wh[i] = h;
    wl[i] = (_Float16)(x - (float)h);
}

// ---------- K2: z[b][c][p] fp32 -> zTh[pix][c] fp16 (transpose + round) ----------
__global__ __launch_bounds__(256) void split_zt_k(
    const float* __restrict__ z, _Float16* __restrict__ zTh)
{
    __shared__ float t[64][68];
    const int tid = threadIdx.x;
    const int pt  = blockIdx.x >> 2;
    const int ct  = blockIdx.x & 3;
    const int b   = pt >> 6;
    const int p0  = (pt & 63) << 6;
    const int c0  = ct << 6;
    const float* zb = z + ((size_t)b * CCH + c0) * HWP + p0;
    {
        const int px4 = tid & 15, cr = tid >> 4;
#pragma unroll
        for (int it = 0; it < 4; ++it) {
            const int c = it * 16 + cr;
            const float4 v = *(const float4*)(zb + (size_t)c * HWP + px4 * 4);
            *(float4*)&t[c][px4 * 4] = v;
        }
    }
    __syncthreads();
    {
        const int c8 = tid & 7, pxl = tid >> 3;
#pragma unroll
        for (int it = 0; it < 2; ++it) {
            const int px = it * 32 + pxl;
            _Float16 hv[8];
#pragma unroll
            for (int i = 0; i < 8; ++i)
                hv[i] = (_Float16)t[c8 * 8 + i][px];
            *(h8*)(zTh + (size_t)(pt * 64 + px) * CCH + c0 + c8 * 8) = *(const h8*)hv;
        }
    }
}

// ---------- K3: MFMA partial logits + per-pixel-per-ntile top2 ----------
// (unchanged from R4 — numerically validated there; only partial buffers moved)
__global__ __launch_bounds__(256, 4) void mfma_part_k(
    const _Float16* __restrict__ zTh,
    const _Float16* __restrict__ wh, const _Float16* __restrict__ wl,
    const float* __restrict__ bias,
    float* __restrict__ pb, float* __restrict__ ps, unsigned short* __restrict__ pi)
{
    __shared__ __align__(16) char smem[27648];   // A 8K | Bh 8K | Bl 8K | merge 3K
    float* s_best = (float*)(smem + 24576);
    float* s_sec  = (float*)(smem + 24576 + 1024);
    int*   s_idx  = (int*)  (smem + 24576 + 2048);

    const int tid = threadIdx.x;
    const int l   = tid & 63;
    const int wv  = tid >> 6;
    const int c15 = l & 15, g = l >> 4;
    const int mhalf = wv >> 1, nhalf = wv & 1;
    const int pxt  = blockIdx.x >> 3;
    const int nt   = blockIdx.x & 7;
    const int pix0 = pxt * 128;
    const int n0   = nt * 128;
    const int srow = l >> 2, scol = l & 3;

    f4 acc[4][4];
#pragma unroll
    for (int mf = 0; mf < 4; ++mf)
#pragma unroll
        for (int nf = 0; nf < 4; ++nf) acc[mf][nf] = (f4)0.f;

#pragma unroll 1
    for (int kc = 0; kc < 8; ++kc) {
        __syncthreads();
        const int koff = kc * 32 + scol * 8;
#pragma unroll
        for (int t = 0; t < 2; ++t) {
            const int i = wv * 2 + t;
            gl_lds16(zTh + (size_t)(pix0 + i * 16 + srow) * CCH + koff, smem + i * 1024);
            gl_lds16(wh  + (size_t)(n0   + i * 16 + srow) * CCH + koff, smem + 8192  + i * 1024);
            gl_lds16(wl  + (size_t)(n0   + i * 16 + srow) * CCH + koff, smem + 16384 + i * 1024);
        }
        __syncthreads();
        h8 ah[4];
#pragma unroll
        for (int mf = 0; mf < 4; ++mf)
            ah[mf] = *(const h8*)(smem + (mhalf * 64 + mf * 16 + c15) * 64 + g * 16);
#pragma unroll
        for (int nf = 0; nf < 4; ++nf) {
            const int nrow = nhalf * 64 + nf * 16 + c15;
            const h8 bh = *(const h8*)(smem + 8192  + nrow * 64 + g * 16);
            const h8 bl = *(const h8*)(smem + 16384 + nrow * 64 + g * 16);
#pragma unroll
            for (int mf = 0; mf < 4; ++mf) {
                acc[mf][nf] = __builtin_amdgcn_mfma_f32_16x16x32_f16(ah[mf], bh, acc[mf][nf], 0, 0, 0);
                acc[mf][nf] = __builtin_amdgcn_mfma_f32_16x16x32_f16(ah[mf], bl, acc[mf][nf], 0, 0, 0);
            }
        }
    }

    float best[16], sec[16]; int bidx[16];
#pragma unroll
    for (int s = 0; s < 16; ++s) { best[s] = -INFINITY; sec[s] = -INFINITY; bidx[s] = 0; }
#pragma unroll
    for (int nf = 0; nf < 4; ++nf) {
        const int n_abs = n0 + nhalf * 64 + nf * 16 + c15;
        const float bv = bias[n_abs];
#pragma unroll
        for (int mf = 0; mf < 4; ++mf)
#pragma unroll
            for (int r = 0; r < 4; ++r) {
                const float v = acc[mf][nf][r] + bv;
                const int s = mf * 4 + r;
                if (v > best[s]) { sec[s] = best[s]; best[s] = v; bidx[s] = n_abs; }
                else if (v > sec[s]) sec[s] = v;
            }
    }
#pragma unroll
    for (int d = 1; d < 16; d <<= 1) {
#pragma unroll
        for (int s = 0; s < 16; ++s) {
            const float ob = __shfl_xor(best[s], d, 64);
            const float os = __shfl_xor(sec[s], d, 64);
            const int   oi = __shfl_xor(bidx[s], d, 64);
            if (ob > best[s])       { sec[s] = fmaxf(best[s], os); best[s] = ob; bidx[s] = oi; }
            else if (ob == best[s]) { sec[s] = ob; bidx[s] = (oi < bidx[s]) ? oi : bidx[s]; }
            else                    { sec[s] = fmaxf(sec[s], ob); }
        }
    }
#pragma unroll
    for (int s = 0; s < 16; ++s) {
        if (c15 == s) {
            const int pxl = mhalf * 64 + (s >> 2) * 16 + g * 4 + (s & 3);
            s_best[nhalf * 128 + pxl] = best[s];
            s_sec [nhalf * 128 + pxl] = sec[s];
            s_idx [nhalf * 128 + pxl] = bidx[s];
        }
    }
    __syncthreads();
    if (tid < 128) {
        float b0 = s_best[tid], s0 = s_sec[tid]; int i0 = s_idx[tid];
        const float ob = s_best[128 + tid], os = s_sec[128 + tid];
        const int   oi = s_idx[128 + tid];
        if (ob > b0)       { s0 = fmaxf(b0, os); b0 = ob; i0 = oi; }
        else if (ob == b0) { s0 = ob; if (oi < i0) i0 = oi; }
        else               { s0 = fmaxf(s0, ob); }
        const size_t o = ((size_t)pxt * 8 + nt) * 128 + tid;
        pb[o] = b0; ps[o] = s0; pi[o] = (unsigned short)i0;
    }
}

// ---------- K4a: merge partials + rare exact-fp32 fixup -> ind + idx16 ----------
__global__ __launch_bounds__(256) void merge_fix_k(
    const float* __restrict__ z, const float* __restrict__ w,
    const float* __restrict__ bias,
    const float* __restrict__ pb, const float* __restrict__ ps,
    const unsigned short* __restrict__ pi,
    unsigned short* __restrict__ idx16,
    float* __restrict__ out)
{
    __shared__ int   indsh[64];
    __shared__ float gaps[64];
    __shared__ float redv[256];
    __shared__ int   redi[256];

    const int tid = threadIdx.x;
    const int blk = blockIdx.x;
    const int b = blk >> 6, p0 = (blk & 63) << 6;
    const int pix0 = blk * 64;

    if (tid < 64) {
        const int pxg = pix0 + tid;
        const int pxt = pxg >> 7, pxl = pxg & 127;
        float b0 = -INFINITY, s0 = -INFINITY; int i0 = 0;
#pragma unroll
        for (int nt = 0; nt < 8; ++nt) {
            const size_t o = ((size_t)pxt * 8 + nt) * 128 + pxl;
            const float ob = pb[o], os = ps[o];
            const int   oi = (int)pi[o];
            if (ob > b0)       { s0 = fmaxf(b0, os); b0 = ob; i0 = oi; }
            else if (ob == b0) { s0 = ob; if (oi < i0) i0 = oi; }
            else               { s0 = fmaxf(s0, ob); }
        }
        indsh[tid] = i0;
        gaps[tid]  = b0 - s0;
    }
    __syncthreads();

    for (int px = 0; px < 64; ++px) {
        if (gaps[px] < MARGIN) {   // block-uniform; rare (~2% of pixels)
            const float* zp = z + (size_t)b * CCH * HWP + p0 + px;
            const float* w0 = w + (size_t)tid * 4 * CCH;
            float a[4];
#pragma unroll
            for (int j = 0; j < 4; ++j) a[j] = bias[tid * 4 + j];
            for (int c = 0; c < CCH; ++c) {
                const float zv = zp[(size_t)c * HWP];
#pragma unroll
                for (int j = 0; j < 4; ++j) a[j] = fmaf(w0[j * CCH + c], zv, a[j]);
            }
            float bv = a[0]; int bi = tid * 4;
#pragma unroll
            for (int j = 1; j < 4; ++j)
                if (a[j] > bv) { bv = a[j]; bi = tid * 4 + j; }
            redv[tid] = bv; redi[tid] = bi;
            __syncthreads();
            if (tid < 64) {
                float v = redv[tid]; int i = redi[tid];
                for (int t2 = tid + 64; t2 < 256; t2 += 64) {
                    const float v2 = redv[t2]; const int i2 = redi[t2];
                    if (v2 > v || (v2 == v && i2 < i)) { v = v2; i = i2; }
                }
                redv[tid] = v; redi[tid] = i;
            }
            __syncthreads();
            if (tid == 0) {
                float v = redv[0]; int i = redi[0];
                for (int t2 = 1; t2 < 64; ++t2) {
                    const float v2 = redv[t2]; const int i2 = redi[t2];
                    if (v2 > v || (v2 == v && i2 < i)) { v = v2; i = i2; }
                }
                indsh[px] = i;
            }
            __syncthreads();
        }
    }

    if (tid < 64) {
        out[ZQ_SIZE + 1 + pix0 + tid] = (float)indsh[tid];
        idx16[pix0 + tid] = (unsigned short)indsh[tid];
    }
    if (blk == 0 && tid == 0) out[ZQ_SIZE] = 0.0f;
}

// ---------- K5: gather epilogue (overwrites z_q incl. dead zTh/partials) ----------
__global__ __launch_bounds__(256) void gather_k(
    const float* __restrict__ embed, const unsigned short* __restrict__ idx16,
    float* __restrict__ out)
{
    __shared__ __align__(16) float tile[64][257];
    __shared__ int indsh[64];

    const int tid = threadIdx.x;
    const int blk = blockIdx.x;
    const int b = blk >> 6, p0 = (blk & 63) << 6;
    const int pix0 = blk * 64;

    if (tid < 64) indsh[tid] = (int)idx16[pix0 + tid];
    __syncthreads();

    const int lq = tid & 63, wq = tid >> 6;
    for (int it = 0; it < 16; ++it) {
        const int p   = it * 4 + wq;
        const int row = indsh[p];
        const float4 e = *(const float4*)(embed + (size_t)row * DD + lq * 4);
        tile[p][lq * 4 + 0] = e.x;
        tile[p][lq * 4 + 1] = e.y;
        tile[p][lq * 4 + 2] = e.z;
        tile[p][lq * 4 + 3] = e.w;
    }
    __syncthreads();
    float* outz = out + (size_t)b * DD * HWP + p0;
    for (int dd = 0; dd < 64; ++dd) {
        const int d = dd * 4 + wq;
        outz[(size_t)d * HWP + lq] = tile[lq][d];
    }
}

extern "C" void kernel_launch(void* const* d_in, const int* in_sizes, int n_in,
                              void* d_out, int out_size, void* d_ws, size_t ws_size,
                              hipStream_t stream) {
    const float* z     = (const float*)d_in[0];
    const float* w     = (const float*)d_in[1];
    const float* bias  = (const float*)d_in[2];
    const float* embed = (const float*)d_in[3];
    float* out = (float*)d_out;

    // ws (1.0625 MB total — within the R3-proven budget):
    //   wh 512K | wl 512K | idx16 64K
    _Float16* wh = (_Float16*)d_ws;
    _Float16* wl = (_Float16*)((char*)d_ws + 524288);
    unsigned short* idx16 = (unsigned short*)((char*)d_ws + 1048576);

    // d_out scratch (dead before gather_k overwrites with z_q):
    //   zTh [0,16MB) | pb [16,17MB) | ps [17,18MB) | pi [18,18.5MB)
    _Float16* zTh = (_Float16*)d_out;
    float* pb = (float*)((char*)d_out + 16777216);
    float* ps = (float*)((char*)d_out + 17825792);
    unsigned short* pi = (unsigned short*)((char*)d_out + 18874368);

    hipLaunchKernelGGL(split_w_k,   dim3(1024), dim3(256), 0, stream, w, wh, wl);
    hipLaunchKernelGGL(split_zt_k,  dim3(2048), dim3(256), 0, stream, z, zTh);
    hipLaunchKernelGGL(mfma_part_k, dim3(2048), dim3(256), 0, stream,
                       zTh, wh, wl, bias, pb, ps, pi);
    hipLaunchKernelGGL(merge_fix_k, dim3(512),  dim3(256), 0, stream,
                       z, w, bias, pb, ps, pi, idx16, out);
    hipLaunchKernelGGL(gather_k,    dim3(512),  dim3(256), 0, stream,
                       embed, idx16, out);
}

// Round 6
// 362.141 us; speedup vs baseline: 1.3523x; 1.3523x over previous
//
#include <hip/hip_runtime.h>
#include <math.h>

#define HWP 4096
#define CCH 256
#define NN  1024
#define DD  256
#define ZQ_SIZE (8 * DD * HWP)       // 8388608 floats = 33554432 B
#define MARGIN 2e-3f

typedef _Float16 h8 __attribute__((ext_vector_type(8)));
typedef float    f4 __attribute__((ext_vector_type(4)));

__device__ __forceinline__ void gl_lds16(const _Float16* g, void* lds) {
    __builtin_amdgcn_global_load_lds(
        (const __attribute__((address_space(1))) unsigned int*)(g),
        (__attribute__((address_space(3))) unsigned int*)(lds),
        16, 0, 0);
}

// ---------- K1: split w -> wh/wl fp16 [1024][256] ----------
__global__ __launch_bounds__(256) void split_w_k(
    const float* __restrict__ w, _Float16* __restrict__ wh, _Float16* __restrict__ wl)
{
    const int i = blockIdx.x * 256 + threadIdx.x;
    const float x = w[i];
    const _Float16 h = (_Float16)x;
    wh[i] = h;
    wl[i] = (_Float16)(x - (float)h);
}

// ---------- K2: z[b][c][p] fp32 -> zTh[pix][c] fp16 (transpose + round) ----------
__global__ __launch_bounds__(256) void split_zt_k(
    const float* __restrict__ z, _Float16* __restrict__ zTh)
{
    __shared__ float t[64][68];
    const int tid = threadIdx.x;
    const int pt  = blockIdx.x >> 2;
    const int ct  = blockIdx.x & 3;
    const int b   = pt >> 6;
    const int p0  = (pt & 63) << 6;
    const int c0  = ct << 6;
    const float* zb = z + ((size_t)b * CCH + c0) * HWP + p0;
    {
        const int px4 = tid & 15, cr = tid >> 4;
#pragma unroll
        for (int it = 0; it < 4; ++it) {
            const int c = it * 16 + cr;
            const float4 v = *(const float4*)(zb + (size_t)c * HWP + px4 * 4);
            *(float4*)&t[c][px4 * 4] = v;
        }
    }
    __syncthreads();
    {
        const int c8 = tid & 7, pxl = tid >> 3;
#pragma unroll
        for (int it = 0; it < 2; ++it) {
            const int px = it * 32 + pxl;
            _Float16 hv[8];
#pragma unroll
            for (int i = 0; i < 8; ++i)
                hv[i] = (_Float16)t[c8 * 8 + i][px];
            *(h8*)(zTh + (size_t)(pt * 64 + px) * CCH + c0 + c8 * 8) = *(const h8*)hv;
        }
    }
}

// ---------- K3: MFMA partial logits + per-pixel-per-ntile top2 ----------
// (byte-identical to R5 — numerically validated)
__global__ __launch_bounds__(256, 4) void mfma_part_k(
    const _Float16* __restrict__ zTh,
    const _Float16* __restrict__ wh, const _Float16* __restrict__ wl,
    const float* __restrict__ bias,
    float* __restrict__ pb, float* __restrict__ ps, unsigned short* __restrict__ pi)
{
    __shared__ __align__(16) char smem[27648];   // A 8K | Bh 8K | Bl 8K | merge 3K
    float* s_best = (float*)(smem + 24576);
    float* s_sec  = (float*)(smem + 24576 + 1024);
    int*   s_idx  = (int*)  (smem + 24576 + 2048);

    const int tid = threadIdx.x;
    const int l   = tid & 63;
    const int wv  = tid >> 6;
    const int c15 = l & 15, g = l >> 4;
    const int mhalf = wv >> 1, nhalf = wv & 1;
    const int pxt  = blockIdx.x >> 3;
    const int nt   = blockIdx.x & 7;
    const int pix0 = pxt * 128;
    const int n0   = nt * 128;
    const int srow = l >> 2, scol = l & 3;

    f4 acc[4][4];
#pragma unroll
    for (int mf = 0; mf < 4; ++mf)
#pragma unroll
        for (int nf = 0; nf < 4; ++nf) acc[mf][nf] = (f4)0.f;

#pragma unroll 1
    for (int kc = 0; kc < 8; ++kc) {
        __syncthreads();
        const int koff = kc * 32 + scol * 8;
#pragma unroll
        for (int t = 0; t < 2; ++t) {
            const int i = wv * 2 + t;
            gl_lds16(zTh + (size_t)(pix0 + i * 16 + srow) * CCH + koff, smem + i * 1024);
            gl_lds16(wh  + (size_t)(n0   + i * 16 + srow) * CCH + koff, smem + 8192  + i * 1024);
            gl_lds16(wl  + (size_t)(n0   + i * 16 + srow) * CCH + koff, smem + 16384 + i * 1024);
        }
        __syncthreads();
        h8 ah[4];
#pragma unroll
        for (int mf = 0; mf < 4; ++mf)
            ah[mf] = *(const h8*)(smem + (mhalf * 64 + mf * 16 + c15) * 64 + g * 16);
#pragma unroll
        for (int nf = 0; nf < 4; ++nf) {
            const int nrow = nhalf * 64 + nf * 16 + c15;
            const h8 bh = *(const h8*)(smem + 8192  + nrow * 64 + g * 16);
            const h8 bl = *(const h8*)(smem + 16384 + nrow * 64 + g * 16);
#pragma unroll
            for (int mf = 0; mf < 4; ++mf) {
                acc[mf][nf] = __builtin_amdgcn_mfma_f32_16x16x32_f16(ah[mf], bh, acc[mf][nf], 0, 0, 0);
                acc[mf][nf] = __builtin_amdgcn_mfma_f32_16x16x32_f16(ah[mf], bl, acc[mf][nf], 0, 0, 0);
            }
        }
    }

    float best[16], sec[16]; int bidx[16];
#pragma unroll
    for (int s = 0; s < 16; ++s) { best[s] = -INFINITY; sec[s] = -INFINITY; bidx[s] = 0; }
#pragma unroll
    for (int nf = 0; nf < 4; ++nf) {
        const int n_abs = n0 + nhalf * 64 + nf * 16 + c15;
        const float bv = bias[n_abs];
#pragma unroll
        for (int mf = 0; mf < 4; ++mf)
#pragma unroll
            for (int r = 0; r < 4; ++r) {
                const float v = acc[mf][nf][r] + bv;
                const int s = mf * 4 + r;
                if (v > best[s]) { sec[s] = best[s]; best[s] = v; bidx[s] = n_abs; }
                else if (v > sec[s]) sec[s] = v;
            }
    }
#pragma unroll
    for (int d = 1; d < 16; d <<= 1) {
#pragma unroll
        for (int s = 0; s < 16; ++s) {
            const float ob = __shfl_xor(best[s], d, 64);
            const float os = __shfl_xor(sec[s], d, 64);
            const int   oi = __shfl_xor(bidx[s], d, 64);
            if (ob > best[s])       { sec[s] = fmaxf(best[s], os); best[s] = ob; bidx[s] = oi; }
            else if (ob == best[s]) { sec[s] = ob; bidx[s] = (oi < bidx[s]) ? oi : bidx[s]; }
            else                    { sec[s] = fmaxf(sec[s], ob); }
        }
    }
#pragma unroll
    for (int s = 0; s < 16; ++s) {
        if (c15 == s) {
            const int pxl = mhalf * 64 + (s >> 2) * 16 + g * 4 + (s & 3);
            s_best[nhalf * 128 + pxl] = best[s];
            s_sec [nhalf * 128 + pxl] = sec[s];
            s_idx [nhalf * 128 + pxl] = bidx[s];
        }
    }
    __syncthreads();
    if (tid < 128) {
        float b0 = s_best[tid], s0 = s_sec[tid]; int i0 = s_idx[tid];
        const float ob = s_best[128 + tid], os = s_sec[128 + tid];
        const int   oi = s_idx[128 + tid];
        if (ob > b0)       { s0 = fmaxf(b0, os); b0 = ob; i0 = oi; }
        else if (ob == b0) { s0 = ob; if (oi < i0) i0 = oi; }
        else               { s0 = fmaxf(s0, ob); }
        const size_t o = ((size_t)pxt * 8 + nt) * 128 + tid;
        pb[o] = b0; ps[o] = s0; pi[o] = (unsigned short)i0;
    }
}

// ---------- K4a: merge partials + BATCHED exact-fp32 fixup -> ind + idx16 ----------
__global__ __launch_bounds__(256) void merge_fix_k(
    const float* __restrict__ z, const float* __restrict__ w,
    const float* __restrict__ bias,
    const float* __restrict__ pb, const float* __restrict__ ps,
    const unsigned short* __restrict__ pi,
    unsigned short* __restrict__ idx16,
    float* __restrict__ out)
{
    __shared__ int   indsh[64];
    __shared__ float gaps[64];
    __shared__ float redv[256];
    __shared__ int   redi[256];
    __shared__ float zsh[8][256];     // batch z vectors, 8 KB
    __shared__ int   plist[64];
    __shared__ int   pcount;

    const int tid = threadIdx.x;
    const int blk = blockIdx.x;
    const int b = blk >> 6, p0 = (blk & 63) << 6;
    const int pix0 = blk * 64;

    if (tid < 64) {
        const int pxg = pix0 + tid;
        const int pxt = pxg >> 7, pxl = pxg & 127;
        float b0 = -INFINITY, s0 = -INFINITY; int i0 = 0;
#pragma unroll
        for (int nt = 0; nt < 8; ++nt) {
            const size_t o = ((size_t)pxt * 8 + nt) * 128 + pxl;
            const float ob = pb[o], os = ps[o];
            const int   oi = (int)pi[o];
            if (ob > b0)       { s0 = fmaxf(b0, os); b0 = ob; i0 = oi; }
            else if (ob == b0) { s0 = ob; if (oi < i0) i0 = oi; }
            else               { s0 = fmaxf(s0, ob); }
        }
        indsh[tid] = i0;
        gaps[tid]  = b0 - s0;
    }
    __syncthreads();
    if (tid == 0) {
        int cnt = 0;
        for (int px = 0; px < 64; ++px)
            if (gaps[px] < MARGIN) plist[cnt++] = px;
        pcount = cnt;
    }
    __syncthreads();
    const int npx = pcount;

    for (int base = 0; base < npx; base += 8) {
        const int nb = (npx - base < 8) ? (npx - base) : 8;
        // Stage batch z vectors: one independent load per thread per pixel.
        for (int i = 0; i < nb; ++i)
            zsh[i][tid] = z[((size_t)b * CCH + tid) * HWP + p0 + plist[base + i]];
        __syncthreads();
        // One pass over w serves all nb pixels. Thread tid owns n=tid*4..+3.
        float acc[8][4];
#pragma unroll
        for (int i = 0; i < 8; ++i)
#pragma unroll
            for (int j = 0; j < 4; ++j) acc[i][j] = bias[tid * 4 + j];
        const float* w0 = w + (size_t)tid * 4 * CCH;
        for (int c4 = 0; c4 < 64; ++c4) {
            float4 wr[4];
#pragma unroll
            for (int j = 0; j < 4; ++j)
                wr[j] = *(const float4*)(w0 + j * CCH + c4 * 4);
            for (int i = 0; i < nb; ++i) {
                const float4 zv = *(const float4*)&zsh[i][c4 * 4];
#pragma unroll
                for (int j = 0; j < 4; ++j) {
                    acc[i][j] = fmaf(wr[j].x, zv.x, acc[i][j]);
                    acc[i][j] = fmaf(wr[j].y, zv.y, acc[i][j]);
                    acc[i][j] = fmaf(wr[j].z, zv.z, acc[i][j]);
                    acc[i][j] = fmaf(wr[j].w, zv.w, acc[i][j]);
                }
            }
        }
        // Per-pixel argmax reduce (validated pattern).
        for (int i = 0; i < nb; ++i) {
            float bv = acc[i][0]; int bi = tid * 4;
#pragma unroll
            for (int j = 1; j < 4; ++j)
                if (acc[i][j] > bv) { bv = acc[i][j]; bi = tid * 4 + j; }
            redv[tid] = bv; redi[tid] = bi;
            __syncthreads();
            if (tid < 64) {
                float v = redv[tid]; int ii = redi[tid];
                for (int t2 = tid + 64; t2 < 256; t2 += 64) {
                    const float v2 = redv[t2]; const int i2 = redi[t2];
                    if (v2 > v || (v2 == v && i2 < ii)) { v = v2; ii = i2; }
                }
                redv[tid] = v; redi[tid] = ii;
            }
            __syncthreads();
            if (tid == 0) {
                float v = redv[0]; int ii = redi[0];
                for (int t2 = 1; t2 < 64; ++t2) {
                    const float v2 = redv[t2]; const int i2 = redi[t2];
                    if (v2 > v || (v2 == v && i2 < ii)) { v = v2; ii = i2; }
                }
                indsh[plist[base + i]] = ii;
            }
            __syncthreads();   // also protects zsh before next batch's staging
        }
    }

    if (tid < 64) {
        out[ZQ_SIZE + 1 + pix0 + tid] = (float)indsh[tid];
        idx16[pix0 + tid] = (unsigned short)indsh[tid];
    }
    if (blk == 0 && tid == 0) out[ZQ_SIZE] = 0.0f;
}

// ---------- K5: gather epilogue (overwrites z_q incl. dead zTh/partials) ----------
__global__ __launch_bounds__(256) void gather_k(
    const float* __restrict__ embed, const unsigned short* __restrict__ idx16,
    float* __restrict__ out)
{
    __shared__ __align__(16) float tile[64][257];
    __shared__ int indsh[64];

    const int tid = threadIdx.x;
    const int blk = blockIdx.x;
    const int b = blk >> 6, p0 = (blk & 63) << 6;
    const int pix0 = blk * 64;

    if (tid < 64) indsh[tid] = (int)idx16[pix0 + tid];
    __syncthreads();

    const int lq = tid & 63, wq = tid >> 6;
    for (int it = 0; it < 16; ++it) {
        const int p   = it * 4 + wq;
        const int row = indsh[p];
        const float4 e = *(const float4*)(embed + (size_t)row * DD + lq * 4);
        tile[p][lq * 4 + 0] = e.x;
        tile[p][lq * 4 + 1] = e.y;
        tile[p][lq * 4 + 2] = e.z;
        tile[p][lq * 4 + 3] = e.w;
    }
    __syncthreads();
    float* outz = out + (size_t)b * DD * HWP + p0;
    for (int dd = 0; dd < 64; ++dd) {
        const int d = dd * 4 + wq;
        outz[(size_t)d * HWP + lq] = tile[lq][d];
    }
}

extern "C" void kernel_launch(void* const* d_in, const int* in_sizes, int n_in,
                              void* d_out, int out_size, void* d_ws, size_t ws_size,
                              hipStream_t stream) {
    const float* z     = (const float*)d_in[0];
    const float* w     = (const float*)d_in[1];
    const float* bias  = (const float*)d_in[2];
    const float* embed = (const float*)d_in[3];
    float* out = (float*)d_out;

    // ws (1.0625 MB — within proven budget): wh 512K | wl 512K | idx16 64K
    _Float16* wh = (_Float16*)d_ws;
    _Float16* wl = (_Float16*)((char*)d_ws + 524288);
    unsigned short* idx16 = (unsigned short*)((char*)d_ws + 1048576);

    // d_out scratch (dead before gather_k overwrites with z_q):
    //   zTh [0,16MB) | pb [16,17MB) | ps [17,18MB) | pi [18,18.5MB)
    _Float16* zTh = (_Float16*)d_out;
    float* pb = (float*)((char*)d_out + 16777216);
    float* ps = (float*)((char*)d_out + 17825792);
    unsigned short* pi = (unsigned short*)((char*)d_out + 18874368);

    hipLaunchKernelGGL(split_w_k,   dim3(1024), dim3(256), 0, stream, w, wh, wl);
    hipLaunchKernelGGL(split_zt_k,  dim3(2048), dim3(256), 0, stream, z, zTh);
    hipLaunchKernelGGL(mfma_part_k, dim3(2048), dim3(256), 0, stream,
                       zTh, wh, wl, bias, pb, ps, pi);
    hipLaunchKernelGGL(merge_fix_k, dim3(512),  dim3(256), 0, stream,
                       z, w, bias, pb, ps, pi, idx16, out);
    hipLaunchKernelGGL(gather_k,    dim3(512),  dim3(256), 0, stream,
                       embed, idx16, out);
}